// Round 4
// baseline (184.178 us; speedup 1.0000x reference)
//
#include <hip/hip_runtime.h>
#include <cstdint>

typedef unsigned long long u64;

#define CH 4096            // local sort chunk size
#define TOPK 2048          // truncated top-K kept per chunk / final candidate count
#define MW2 (TOPK / 64)    // 32 suppression words
#define SCAN_T 256
#define FB_WORDS 1024      // fallback alive-bitmap capacity (64K boxes)

// ascending-sortable key; smaller = better (higher score). invalid/padding -> top region
__device__ __forceinline__ u64 score_key(float s, float thr, int idx, int N) {
    u64 key = ~0ull;
    if (idx < N) {
        unsigned u = __float_as_uint(s);
        u ^= (u >> 31) ? 0xFFFFFFFFu : 0x80000000u;   // orderable ascending
        unsigned ud = ~u;                              // descending score
        if (!(s > thr)) ud = 0xFFFFFFFFu;              // below threshold -> invalid
        key = ((u64)ud << 32) | (unsigned)idx;         // stable: lower idx first
    }
    return key;
}

// ---- 1. fused key-build + local bitonic sort of CH + truncate to TOPK + valid count ----
__global__ __launch_bounds__(1024) void local_sort_kernel(
        const float* __restrict__ scores, const float* __restrict__ scoreThrPtr,
        u64* __restrict__ outKeys, int* __restrict__ validCnt, int N) {
    __shared__ u64 lk[CH];
    __shared__ int vred;
    int t = threadIdx.x;
    int base = blockIdx.x * CH;
    float thr = *scoreThrPtr;
    if (t == 0) vred = 0;
    __syncthreads();
    int myv = 0;
    for (int u = t; u < CH; u += 1024) {
        int i = base + u;
        float s = (i < N) ? scores[i] : 0.0f;
        u64 k = score_key(s, thr, i, N);
        if ((unsigned)(k >> 32) != 0xFFFFFFFFu) ++myv;
        lk[u] = k;
    }
    atomicAdd(&vred, myv);
    __syncthreads();
    if (t == 0) validCnt[blockIdx.x] = vred;
    for (int k = 2; k <= CH; k <<= 1) {
        for (int j = k >> 1; j > 0; j >>= 1) {
            for (int p = t; p < CH / 2; p += 1024) {
                int i = ((p & ~(j - 1)) << 1) | (p & (j - 1));
                int l = i + j;
                bool up = ((i & k) == 0);
                u64 a = lk[i], b = lk[l];
                if ((a > b) == up) { lk[i] = b; lk[l] = a; }
            }
            __syncthreads();
        }
    }
    for (int u = t; u < TOPK; u += 1024) outKeys[(size_t)blockIdx.x * TOPK + u] = lk[u];
}

// ---- 2. pairwise bitonic merge of two sorted TOPK runs, truncate to TOPK ----
__global__ __launch_bounds__(1024) void merge_kernel(const u64* __restrict__ in,
                                                     u64* __restrict__ out) {
    __shared__ u64 s[2 * TOPK];
    int t = threadIdx.x;
    const u64* A = in + (size_t)(2 * blockIdx.x) * TOPK;
    const u64* B = A + TOPK;
    s[t] = A[t]; s[t + 1024] = A[t + 1024];
    s[2 * TOPK - 1 - t] = B[t];                 // B reversed -> bitonic sequence
    s[2 * TOPK - 1 - (t + 1024)] = B[t + 1024];
    __syncthreads();
    for (int j = TOPK; j > 0; j >>= 1) {
        for (int p = t; p < TOPK; p += 1024) {
            int i = ((p & ~(j - 1)) << 1) | (p & (j - 1));
            int l = i + j;
            u64 a = s[i], b = s[l];
            if (a > b) { s[i] = b; s[l] = a; }
        }
        __syncthreads();
    }
    out[(size_t)blockIdx.x * TOPK + t] = s[t];
    out[(size_t)blockIdx.x * TOPK + t + 1024] = s[t + 1024];
}

// ---- 3. final merge fused with gather of boxes/areas/sorig/validw + validTotal ----
__global__ __launch_bounds__(1024) void merge_final_kernel(
        const u64* __restrict__ in, const float* __restrict__ boxes,
        float* __restrict__ sx1, float* __restrict__ sy1,
        float* __restrict__ sx2, float* __restrict__ sy2,
        float* __restrict__ areas, int* __restrict__ sorig,
        u64* __restrict__ validw, const int* __restrict__ validCnt,
        int nch, int* __restrict__ validTotal) {
    __shared__ u64 s[2 * TOPK];
    int t = threadIdx.x;
    const u64* A = in;
    const u64* B = in + TOPK;
    s[t] = A[t]; s[t + 1024] = A[t + 1024];
    s[2 * TOPK - 1 - t] = B[t];
    s[2 * TOPK - 1 - (t + 1024)] = B[t + 1024];
    __syncthreads();
    for (int j = TOPK; j > 0; j >>= 1) {
        for (int p = t; p < TOPK; p += 1024) {
            int i = ((p & ~(j - 1)) << 1) | (p & (j - 1));
            int l = i + j;
            u64 a = s[i], b = s[l];
            if (a > b) { s[i] = b; s[l] = a; }
        }
        __syncthreads();
    }
    int lane = t & 63;
    for (int r = t; r < TOPK; r += 1024) {
        u64 k = s[r];
        unsigned hi = (unsigned)(k >> 32), lo = (unsigned)k;
        bool valid = (hi != 0xFFFFFFFFu);
        u64 ball = __ballot(valid);
        if (lane == 0) validw[r >> 6] = ball;
        float4 b; b.x = 0.f; b.y = 0.f; b.z = 0.f; b.w = 0.f;
        if (valid) b = ((const float4*)boxes)[lo];
        sx1[r] = b.x; sy1[r] = b.y; sx2[r] = b.z; sy2[r] = b.w;
        areas[r] = (b.z - b.x) * (b.w - b.y);
        sorig[r] = valid ? (int)lo : 0;
    }
    if (t == 0) {
        int tot = 0;
        for (int i = 0; i < nch; ++i) tot += validCnt[i];
        *validTotal = tot;
    }
}

// ---- 4. pairwise IoU mask over top-TOPK (upper triangle) + transposed diagonal ----
__global__ __launch_bounds__(64) void mask2_kernel(
        const float* __restrict__ sx1, const float* __restrict__ sy1,
        const float* __restrict__ sx2, const float* __restrict__ sy2,
        const float* __restrict__ areas, const float* __restrict__ iouThrPtr,
        u64* __restrict__ mask2, u64* __restrict__ diagT) {
    int wi = blockIdx.x, wj = blockIdx.y;
    if (wj < wi) return;                       // uniform block exit, before barriers
    __shared__ float jx1[64], jy1[64], jx2[64], jy2[64], ja[64];
    __shared__ u64 rowLDS[64];
    int t = threadIdx.x;
    int j0 = wj << 6;
    jx1[t] = sx1[j0 + t]; jy1[t] = sy1[j0 + t];
    jx2[t] = sx2[j0 + t]; jy2[t] = sy2[j0 + t];
    ja[t] = areas[j0 + t];
    __syncthreads();
    int i = (wi << 6) + t;
    float thr = *iouThrPtr;
    float ix1 = sx1[i], iy1 = sy1[i], ix2 = sx2[i], iy2 = sy2[i], ia = areas[i];
    u64 bits = 0;
    for (int jj = 0; jj < 64; ++jj) {
        int j = j0 + jj;
        if (j > i) {
            float xx1 = fmaxf(ix1, jx1[jj]);
            float yy1 = fmaxf(iy1, jy1[jj]);
            float xx2 = fminf(ix2, jx2[jj]);
            float yy2 = fminf(iy2, jy2[jj]);
            float ww = fmaxf(xx2 - xx1, 0.0f);
            float hh = fmaxf(yy2 - yy1, 0.0f);
            float inter = ww * hh;
            float uni = fmaxf(ia + ja[jj] - inter, 1e-6f);
            if (inter / uni >= thr) bits |= 1ull << jj;
        }
    }
    mask2[(size_t)i * MW2 + wj] = bits;
    if (wi == wj) {
        rowLDS[t] = bits;
        __syncthreads();
        u64 col = 0;
        for (int r = 0; r < 64; ++r) col |= ((rowLDS[r] >> t) & 1ull) << r;
        diagT[(wi << 6) + t] = col;            // bit r of word t: r suppresses t
    }
}

// ---- 5. chunk-wise greedy scan with incremental LDS suppression ----
__global__ __launch_bounds__(SCAN_T) void scan2_kernel(
        const u64* __restrict__ mask2, const u64* __restrict__ diagT,
        const u64* __restrict__ validw, const int* __restrict__ sorig,
        const int* __restrict__ validTotalPtr,
        int* __restrict__ out, int* __restrict__ flagDone, int maxOut) {
    __shared__ u64 diagLDS[MW2 * 64];          // 16 KB
    __shared__ u64 Ssup[MW2];
    __shared__ u64 validwLDS[MW2];
    __shared__ int selLDS[TOPK];
    __shared__ int cntSh;
    __shared__ int validScanSh;
    int tid = threadIdx.x, lane = tid & 63, wave = tid >> 6;

    for (int k = tid; k < MW2 * 64; k += SCAN_T) diagLDS[k] = diagT[k];
    if (tid < MW2) { Ssup[tid] = 0ull; validwLDS[tid] = validw[tid]; }
    if (tid == 0) { cntSh = 0; validScanSh = 0; }
    __syncthreads();

    int cnt = 0;
    for (int w = 0; w < MW2; ++w) {
        if (wave == 0) {                       // serial greedy resolve of chunk w
            u64 col = diagLDS[(w << 6) | lane];
            u64 avail = validwLDS[w] & ~Ssup[w];
            bool alive = (avail >> lane) & 1ull;
            u64 c = __ballot(alive);
            u64 selmask = 0;
            int room = maxOut - cnt;
            while (c != 0ull && room > 0) {
                int b = __builtin_ctzll(c);
                selmask |= 1ull << b; --room;
                alive = alive && !((col >> b) & 1ull);
                u64 rest = (b >= 63) ? 0ull : ~((2ull << b) - 1ull);
                c = __ballot(alive) & rest;
            }
            if ((selmask >> lane) & 1ull) {
                int pos = cnt + __popcll(selmask & ((1ull << lane) - 1ull));
                selLDS[pos] = (w << 6) | lane;
            }
            if (lane == 0) cntSh = cnt + __popcll(selmask);
        }
        __syncthreads();
        int base = cnt;
        int ncnt = cntSh;
        int m = ncnt - base;
        int ncols = MW2 - 1 - w;
        if (m > 0 && ncols > 0) {              // incremental Ssup update for future chunks
            int cidx = tid & 31, stripe = tid >> 5;    // 8 stripes x 32 columns
            if (cidx < ncols) {
                int wp = w + 1 + cidx;
                u64 acc = 0;
                for (int k = base + stripe; k < ncnt; k += 8)
                    acc |= mask2[(size_t)selLDS[k] * MW2 + wp];
                if (acc) atomicOr(&Ssup[wp], acc);
            }
        }
        cnt = ncnt;
        __syncthreads();
        if (cnt >= maxOut) break;
    }

    if (tid < MW2) atomicAdd(&validScanSh, __popcll(validwLDS[tid]));
    __syncthreads();
    bool complete = (cnt >= maxOut) || (validScanSh >= *validTotalPtr);
    if (complete) {
        for (int k = tid; k < cnt; k += SCAN_T) out[k] = sorig[selLDS[k]];
        for (int k = cnt + tid; k < maxOut; k += SCAN_T) out[k] = 0;
        if (tid == 0) out[maxOut] = cnt;
    }
    if (tid == 0) *flagDone = complete ? 1 : 0;
}

// ---- 6. sort-free fallback: repeated argmax greedy NMS (runs only if flag==0) ----
__global__ __launch_bounds__(1024) void nms_fallback_kernel(
        const float* __restrict__ boxes, const float* __restrict__ scores,
        const float* __restrict__ iouThrPtr, const float* __restrict__ scoreThrPtr,
        const int* __restrict__ flagDone,
        int* __restrict__ out, int N, int maxOut) {
    if (*flagDone) return;                     // uniform early-exit, before barriers
    __shared__ u64 aliveW[FB_WORDS];
    __shared__ u64 keyRed[16];
    __shared__ u64 winKeySh;
    int tid = threadIdx.x, lane = tid & 63, wave = tid >> 6;
    float sThr = *scoreThrPtr, iThr = *iouThrPtr;
    for (int e0 = wave << 6; e0 < N; e0 += 1024) {
        int e = e0 + lane;
        bool a = (e < N) && (scores[e] > sThr);
        u64 ball = __ballot(a);
        if (lane == 0) aliveW[e0 >> 6] = ball;
    }
    __syncthreads();
    int cnt = 0;
    while (cnt < maxOut) {
        // argmax over alive: key = (orderable score << 32) | ~idx  (ties -> lower idx)
        u64 best = 0;
        for (int e = tid; e < N; e += 1024) {
            if ((aliveW[e >> 6] >> (e & 63)) & 1ull) {
                float s = scores[e];
                unsigned u = __float_as_uint(s);
                u ^= (u >> 31) ? 0xFFFFFFFFu : 0x80000000u;
                u64 k = ((u64)u << 32) | (unsigned)(~e);
                if (k > best) best = k;
            }
        }
#pragma unroll
        for (int off = 32; off >= 1; off >>= 1) {
            u64 o = __shfl_xor(best, off, 64);
            if (o > best) best = o;
        }
        if (lane == 0) keyRed[wave] = best;
        __syncthreads();
        if (tid == 0) {
            u64 b = 0;
            for (int p = 0; p < 16; ++p) if (keyRed[p] > b) b = keyRed[p];
            winKeySh = b;
        }
        __syncthreads();
        u64 wk = winKeySh;
        if (wk == 0ull) break;
        int win = (int)(~(unsigned)wk);
        if (tid == 0) out[cnt] = win;
        ++cnt;
        float4 wb = ((const float4*)boxes)[win];
        float wa = (wb.z - wb.x) * (wb.w - wb.y);
        for (int e0 = wave << 6; e0 < N; e0 += 1024) {
            int e = e0 + lane;
            bool kill = false;
            if (e < N && ((aliveW[e0 >> 6] >> lane) & 1ull)) {
                if (e == win) kill = true;
                else {
                    float4 bb = ((const float4*)boxes)[e];
                    float xx1 = fmaxf(wb.x, bb.x), yy1 = fmaxf(wb.y, bb.y);
                    float xx2 = fminf(wb.z, bb.z), yy2 = fminf(wb.w, bb.w);
                    float inter = fmaxf(xx2 - xx1, 0.0f) * fmaxf(yy2 - yy1, 0.0f);
                    float ba = (bb.z - bb.x) * (bb.w - bb.y);
                    float uni = fmaxf(wa + ba - inter, 1e-6f);
                    kill = (inter / uni >= iThr);
                }
            }
            u64 kb = __ballot(kill);
            if (lane == 0 && kb) aliveW[e0 >> 6] &= ~kb;
        }
        __syncthreads();
    }
    for (int k = cnt + tid; k < maxOut; k += 1024) out[k] = 0;
    if (tid == 0) out[maxOut] = cnt;
}

// ---------------- launch ----------------
extern "C" void kernel_launch(void* const* d_in, const int* in_sizes, int n_in,
                              void* d_out, int out_size, void* d_ws, size_t ws_size,
                              hipStream_t stream) {
    const float* boxes       = (const float*)d_in[0];
    const float* scores      = (const float*)d_in[1];
    const float* iouThrPtr   = (const float*)d_in[3];
    const float* scoreThrPtr = (const float*)d_in[4];

    int N = in_sizes[0] / 4;
    int maxOut = out_size - 1;
    int nch = 2;
    while (nch * CH < N) nch <<= 1;            // power-of-two chunk count, >=2

    char* ws = (char*)d_ws;
    size_t off = 0;
    auto take = [&](size_t b) { void* p = ws + off; off = (off + b + 255) & ~(size_t)255; return p; };
    u64*   bufA   = (u64*)  take((size_t)nch * TOPK * 8);
    u64*   bufB   = (u64*)  take((size_t)(nch / 2) * TOPK * 8);
    float* sx1    = (float*)take(TOPK * 4);
    float* sy1    = (float*)take(TOPK * 4);
    float* sx2    = (float*)take(TOPK * 4);
    float* sy2    = (float*)take(TOPK * 4);
    float* areas  = (float*)take(TOPK * 4);
    int*   sorig  = (int*)  take(TOPK * 4);
    u64*   validw = (u64*)  take(MW2 * 8);
    int*   validCnt = (int*)take((size_t)nch * 4);
    int*   validTotal = (int*)take(256);
    u64*   mask2  = (u64*)  take((size_t)TOPK * MW2 * 8);
    u64*   diagT  = (u64*)  take((size_t)MW2 * 64 * 8);
    int*   flag   = (int*)  take(256);
    (void)ws_size;

    local_sort_kernel<<<nch, 1024, 0, stream>>>(scores, scoreThrPtr, bufA, validCnt, N);

    u64* src = bufA;
    u64* dst = bufB;
    int cur = nch;
    while (cur > 2) {
        merge_kernel<<<cur / 2, 1024, 0, stream>>>(src, dst);
        u64* tmp = src; src = dst; dst = tmp;
        cur >>= 1;
    }
    merge_final_kernel<<<1, 1024, 0, stream>>>(src, boxes, sx1, sy1, sx2, sy2, areas,
                                               sorig, validw, validCnt, nch, validTotal);

    mask2_kernel<<<dim3(MW2, MW2), 64, 0, stream>>>(sx1, sy1, sx2, sy2, areas, iouThrPtr,
                                                    mask2, diagT);

    scan2_kernel<<<1, SCAN_T, 0, stream>>>(mask2, diagT, validw, sorig, validTotal,
                                           (int*)d_out, flag, maxOut);

    nms_fallback_kernel<<<1, 1024, 0, stream>>>(boxes, scores, iouThrPtr, scoreThrPtr,
                                                flag, (int*)d_out, N, maxOut);
}

// Round 5
// 97.718 us; speedup vs baseline: 1.8848x; 1.8848x over previous
//
#include <hip/hip_runtime.h>
#include <cstdint>

typedef unsigned long long u64;

#define CH 4096            // local sort chunk size
#define TOPK 2048          // truncated top-K kept per chunk / final candidate count
#define MW2 (TOPK / 64)    // 32 suppression words
#define SCAN_T 256
#define FB_WORDS 1024      // fallback alive-bitmap capacity (64K boxes)

// ascending-sortable key; smaller = better (higher score). invalid/padding -> top region
__device__ __forceinline__ u64 score_key(float s, float thr, int idx, int N) {
    u64 key = ~0ull;
    if (idx < N) {
        unsigned u = __float_as_uint(s);
        u ^= (u >> 31) ? 0xFFFFFFFFu : 0x80000000u;   // orderable ascending
        unsigned ud = ~u;                              // descending score
        if (!(s > thr)) ud = 0xFFFFFFFFu;              // below threshold -> invalid
        key = ((u64)ud << 32) | (unsigned)idx;         // stable: lower idx first
    }
    return key;
}

// ---- 1. fused key-build + local bitonic sort of CH + truncate to TOPK + valid count ----
__global__ __launch_bounds__(1024) void local_sort_kernel(
        const float* __restrict__ scores, const float* __restrict__ scoreThrPtr,
        u64* __restrict__ outKeys, int* __restrict__ validCnt, int N) {
    __shared__ u64 lk[CH];
    __shared__ int vred;
    int t = threadIdx.x;
    int base = blockIdx.x * CH;
    float thr = *scoreThrPtr;
    if (t == 0) vred = 0;
    __syncthreads();
    int myv = 0;
    for (int u = t; u < CH; u += 1024) {
        int i = base + u;
        float s = (i < N) ? scores[i] : 0.0f;
        u64 k = score_key(s, thr, i, N);
        if ((unsigned)(k >> 32) != 0xFFFFFFFFu) ++myv;
        lk[u] = k;
    }
    atomicAdd(&vred, myv);
    __syncthreads();
    if (t == 0) validCnt[blockIdx.x] = vred;
    for (int k = 2; k <= CH; k <<= 1) {
        for (int j = k >> 1; j > 0; j >>= 1) {
            for (int p = t; p < CH / 2; p += 1024) {
                int i = ((p & ~(j - 1)) << 1) | (p & (j - 1));
                int l = i + j;
                bool up = ((i & k) == 0);
                u64 a = lk[i], b = lk[l];
                if ((a > b) == up) { lk[i] = b; lk[l] = a; }
            }
            __syncthreads();
        }
    }
    for (int u = t; u < TOPK; u += 1024) outKeys[(size_t)blockIdx.x * TOPK + u] = lk[u];
}

// ---- 2. pairwise bitonic merge of two sorted TOPK runs, truncate to TOPK ----
__global__ __launch_bounds__(1024) void merge_kernel(const u64* __restrict__ in,
                                                     u64* __restrict__ out) {
    __shared__ u64 s[2 * TOPK];
    int t = threadIdx.x;
    const u64* A = in + (size_t)(2 * blockIdx.x) * TOPK;
    const u64* B = A + TOPK;
    s[t] = A[t]; s[t + 1024] = A[t + 1024];
    s[2 * TOPK - 1 - t] = B[t];                 // B reversed -> bitonic sequence
    s[2 * TOPK - 1 - (t + 1024)] = B[t + 1024];
    __syncthreads();
    for (int j = TOPK; j > 0; j >>= 1) {
        for (int p = t; p < TOPK; p += 1024) {
            int i = ((p & ~(j - 1)) << 1) | (p & (j - 1));
            int l = i + j;
            u64 a = s[i], b = s[l];
            if (a > b) { s[i] = b; s[l] = a; }
        }
        __syncthreads();
    }
    out[(size_t)blockIdx.x * TOPK + t] = s[t];
    out[(size_t)blockIdx.x * TOPK + t + 1024] = s[t + 1024];
}

// ---- 3. final merge fused with gather of boxes/areas/sorig/validw + validTotal ----
__global__ __launch_bounds__(1024) void merge_final_kernel(
        const u64* __restrict__ in, const float* __restrict__ boxes,
        float* __restrict__ sx1, float* __restrict__ sy1,
        float* __restrict__ sx2, float* __restrict__ sy2,
        float* __restrict__ areas, int* __restrict__ sorig,
        u64* __restrict__ validw, const int* __restrict__ validCnt,
        int nch, int* __restrict__ validTotal) {
    __shared__ u64 s[2 * TOPK];
    int t = threadIdx.x;
    const u64* A = in;
    const u64* B = in + TOPK;
    s[t] = A[t]; s[t + 1024] = A[t + 1024];
    s[2 * TOPK - 1 - t] = B[t];
    s[2 * TOPK - 1 - (t + 1024)] = B[t + 1024];
    __syncthreads();
    for (int j = TOPK; j > 0; j >>= 1) {
        for (int p = t; p < TOPK; p += 1024) {
            int i = ((p & ~(j - 1)) << 1) | (p & (j - 1));
            int l = i + j;
            u64 a = s[i], b = s[l];
            if (a > b) { s[i] = b; s[l] = a; }
        }
        __syncthreads();
    }
    int lane = t & 63;
    for (int r = t; r < TOPK; r += 1024) {
        u64 k = s[r];
        unsigned hi = (unsigned)(k >> 32), lo = (unsigned)k;
        bool valid = (hi != 0xFFFFFFFFu);
        u64 ball = __ballot(valid);
        if (lane == 0) validw[r >> 6] = ball;
        float4 b; b.x = 0.f; b.y = 0.f; b.z = 0.f; b.w = 0.f;
        if (valid) b = ((const float4*)boxes)[lo];
        sx1[r] = b.x; sy1[r] = b.y; sx2[r] = b.z; sy2[r] = b.w;
        areas[r] = (b.z - b.x) * (b.w - b.y);
        sorig[r] = valid ? (int)lo : 0;
    }
    if (t == 0) {
        int tot = 0;
        for (int i = 0; i < nch; ++i) tot += validCnt[i];
        *validTotal = tot;
    }
}

// ---- 4. transposed IoU mask: maskT[j][wi] = rows in chunk wi that suppress j ----
__global__ __launch_bounds__(64) void mask2_kernel(
        const float* __restrict__ sx1, const float* __restrict__ sy1,
        const float* __restrict__ sx2, const float* __restrict__ sy2,
        const float* __restrict__ areas, const float* __restrict__ iouThrPtr,
        u64* __restrict__ maskT, u64* __restrict__ diagT) {
    int wi = blockIdx.x, wj = blockIdx.y;
    if (wj < wi) return;                       // uniform block exit, before barriers
    __shared__ float jx1[64], jy1[64], jx2[64], jy2[64], ja[64];
    __shared__ u64 rowLDS[64];
    int t = threadIdx.x;
    int j0 = wj << 6;
    jx1[t] = sx1[j0 + t]; jy1[t] = sy1[j0 + t];
    jx2[t] = sx2[j0 + t]; jy2[t] = sy2[j0 + t];
    ja[t] = areas[j0 + t];
    __syncthreads();
    int i = (wi << 6) + t;
    float thr = *iouThrPtr;
    float ix1 = sx1[i], iy1 = sy1[i], ix2 = sx2[i], iy2 = sy2[i], ia = areas[i];
    u64 bits = 0;
    for (int jj = 0; jj < 64; ++jj) {
        int j = j0 + jj;
        if (j > i) {
            float xx1 = fmaxf(ix1, jx1[jj]);
            float yy1 = fmaxf(iy1, jy1[jj]);
            float xx2 = fminf(ix2, jx2[jj]);
            float yy2 = fminf(iy2, jy2[jj]);
            float ww = fmaxf(xx2 - xx1, 0.0f);
            float hh = fmaxf(yy2 - yy1, 0.0f);
            float inter = ww * hh;
            float uni = fmaxf(ia + ja[jj] - inter, 1e-6f);
            if (inter / uni >= thr) bits |= 1ull << jj;
        }
    }
    rowLDS[t] = bits;                          // row i over columns of chunk wj
    __syncthreads();
    u64 col = 0;                               // transpose: column (j0+t) over rows of chunk wi
    for (int r = 0; r < 64; ++r) col |= ((rowLDS[r] >> t) & 1ull) << r;
    maskT[(size_t)(j0 + t) * MW2 + wi] = col;
    if (wi == wj) diagT[(wi << 6) + t] = col;  // in-chunk in-edge mask of candidate t
}

// ---- 5. chunk-wise greedy scan: prefetched colmask reduce + ballot fixpoint ----
__global__ __launch_bounds__(SCAN_T) void scan2_kernel(
        const u64* __restrict__ maskT, const u64* __restrict__ diagT,
        const u64* __restrict__ validw, const int* __restrict__ sorig,
        const int* __restrict__ validTotalPtr,
        int* __restrict__ out, int* __restrict__ flagDone, int maxOut) {
    __shared__ u64 diagLDS[TOPK];              // 16 KB: in-edge word per candidate
    __shared__ u64 selw[MW2];                  // selected-so-far bitset
    __shared__ u64 validwLDS[MW2];
    __shared__ u64 ballots[SCAN_T / 64];
    __shared__ int selLDS[TOPK];
    __shared__ int cntSh;
    __shared__ int validScanSh;
    int tid = threadIdx.x, lane = tid & 63, wave = tid >> 6;
    int cc = tid >> 2;                          // column within chunk (0..63)
    int g  = tid & 3;                           // word-group (8 words each)

    for (int k = tid; k < TOPK; k += SCAN_T) diagLDS[k] = diagT[k];
    if (tid < MW2) { selw[tid] = 0ull; validwLDS[tid] = validw[tid]; }
    if (tid == 0) { cntSh = 0; validScanSh = 0; }

    // prefetch chunk 0 colmask words (raw; garbage words masked at use)
    ulonglong2 a0, a1, a2, a3;
    {
        const ulonglong2* p = (const ulonglong2*)(maskT + (size_t)cc * MW2 + g * 8);
        a0 = p[0]; a1 = p[1]; a2 = p[2]; a3 = p[3];
    }
    __syncthreads();

    int cnt = 0;
    for (int w = 0; w < MW2; ++w) {
        // cross-chunk kill reduce: OR over wr<w of maskT[j][wr] & selw[wr]
        u64 wd0 = a0.x, wd1 = a0.y, wd2 = a1.x, wd3 = a1.y;
        u64 wd4 = a2.x, wd5 = a2.y, wd6 = a3.x, wd7 = a3.y;
        int wr0 = g * 8;
        u64 acc = 0;
        if (wr0 + 0 < w) acc |= wd0 & selw[wr0 + 0];
        if (wr0 + 1 < w) acc |= wd1 & selw[wr0 + 1];
        if (wr0 + 2 < w) acc |= wd2 & selw[wr0 + 2];
        if (wr0 + 3 < w) acc |= wd3 & selw[wr0 + 3];
        if (wr0 + 4 < w) acc |= wd4 & selw[wr0 + 4];
        if (wr0 + 5 < w) acc |= wd5 & selw[wr0 + 5];
        if (wr0 + 6 < w) acc |= wd6 & selw[wr0 + 6];
        if (wr0 + 7 < w) acc |= wd7 & selw[wr0 + 7];
        acc |= __shfl_xor(acc, 1, 64);
        acc |= __shfl_xor(acc, 2, 64);          // 4-lane group OR: all lanes of group have full kill
        u64 B = __ballot(acc != 0ull);
        if (lane == 0) ballots[wave] = B;
        // prefetch chunk w+1 (latency hides under resolve)
        if (w + 1 < MW2) {
            const ulonglong2* p = (const ulonglong2*)(maskT + (size_t)((w + 1) * 64 + cc) * MW2 + g * 8);
            a0 = p[0]; a1 = p[1]; a2 = p[2]; a3 = p[3];
        }
        __syncthreads();
        if (wave == 0) {
            // extract cross-kill bit for column 'lane': ballots[lane>>4] bits 4*(lane&15)
            u64 bv = ballots[lane >> 4];
            bool crossk = (bv >> ((lane & 15) << 2)) & 1ull;
            bool alv = ((validwLDS[w] >> lane) & 1ull) && !crossk;
            u64 inm = diagLDS[(w << 6) | lane];  // in-chunk rows that suppress this lane
            // lex-first-MIS fixpoint: sel(b) = alv(b) && !(inm(b) & sel)
            u64 sel = __ballot(alv);
            while (true) {
                bool killed = (inm & sel) != 0ull;
                u64 ns = __ballot(alv && !killed);
                if (ns == sel) break;
                sel = ns;
            }
            int room = maxOut - cnt;
            int tot = __popcll(sel);
            u64 below = (1ull << lane) - 1ull;
            if (tot > room) {                    // cap: keep lowest `room` selected bits
                bool keep = ((sel >> lane) & 1ull) && (__popcll(sel & below) < room);
                sel = __ballot(keep);
                tot = room;
            }
            if ((sel >> lane) & 1ull) {
                int pos = cnt + __popcll(sel & below);
                selLDS[pos] = (w << 6) | lane;
            }
            if (lane == 0) { selw[w] = sel; cntSh = cnt + tot; }
        }
        __syncthreads();
        cnt = cntSh;
        if (cnt >= maxOut) break;
    }

    if (tid < MW2) atomicAdd(&validScanSh, __popcll(validwLDS[tid]));
    __syncthreads();
    bool complete = (cnt >= maxOut) || (validScanSh >= *validTotalPtr);
    if (complete) {
        for (int k = tid; k < cnt; k += SCAN_T) out[k] = sorig[selLDS[k]];
        for (int k = cnt + tid; k < maxOut; k += SCAN_T) out[k] = 0;
        if (tid == 0) out[maxOut] = cnt;
    }
    if (tid == 0) *flagDone = complete ? 1 : 0;
}

// ---- 6. sort-free fallback: repeated argmax greedy NMS (runs only if flag==0) ----
__global__ __launch_bounds__(1024) void nms_fallback_kernel(
        const float* __restrict__ boxes, const float* __restrict__ scores,
        const float* __restrict__ iouThrPtr, const float* __restrict__ scoreThrPtr,
        const int* __restrict__ flagDone,
        int* __restrict__ out, int N, int maxOut) {
    if (*flagDone) return;                     // uniform early-exit, before barriers
    __shared__ u64 aliveW[FB_WORDS];
    __shared__ u64 keyRed[16];
    __shared__ u64 winKeySh;
    int tid = threadIdx.x, lane = tid & 63, wave = tid >> 6;
    float sThr = *scoreThrPtr, iThr = *iouThrPtr;
    for (int e0 = wave << 6; e0 < N; e0 += 1024) {
        int e = e0 + lane;
        bool a = (e < N) && (scores[e] > sThr);
        u64 ball = __ballot(a);
        if (lane == 0) aliveW[e0 >> 6] = ball;
    }
    __syncthreads();
    int cnt = 0;
    while (cnt < maxOut) {
        u64 best = 0;
        for (int e = tid; e < N; e += 1024) {
            if ((aliveW[e >> 6] >> (e & 63)) & 1ull) {
                float s = scores[e];
                unsigned u = __float_as_uint(s);
                u ^= (u >> 31) ? 0xFFFFFFFFu : 0x80000000u;
                u64 k = ((u64)u << 32) | (unsigned)(~e);
                if (k > best) best = k;
            }
        }
#pragma unroll
        for (int off = 32; off >= 1; off >>= 1) {
            u64 o = __shfl_xor(best, off, 64);
            if (o > best) best = o;
        }
        if (lane == 0) keyRed[wave] = best;
        __syncthreads();
        if (tid == 0) {
            u64 b = 0;
            for (int p = 0; p < 16; ++p) if (keyRed[p] > b) b = keyRed[p];
            winKeySh = b;
        }
        __syncthreads();
        u64 wk = winKeySh;
        if (wk == 0ull) break;
        int win = (int)(~(unsigned)wk);
        if (tid == 0) out[cnt] = win;
        ++cnt;
        float4 wb = ((const float4*)boxes)[win];
        float wa = (wb.z - wb.x) * (wb.w - wb.y);
        for (int e0 = wave << 6; e0 < N; e0 += 1024) {
            int e = e0 + lane;
            bool kill = false;
            if (e < N && ((aliveW[e0 >> 6] >> lane) & 1ull)) {
                if (e == win) kill = true;
                else {
                    float4 bb = ((const float4*)boxes)[e];
                    float xx1 = fmaxf(wb.x, bb.x), yy1 = fmaxf(wb.y, bb.y);
                    float xx2 = fminf(wb.z, bb.z), yy2 = fminf(wb.w, bb.w);
                    float inter = fmaxf(xx2 - xx1, 0.0f) * fmaxf(yy2 - yy1, 0.0f);
                    float ba = (bb.z - bb.x) * (bb.w - bb.y);
                    float uni = fmaxf(wa + ba - inter, 1e-6f);
                    kill = (inter / uni >= iThr);
                }
            }
            u64 kb = __ballot(kill);
            if (lane == 0 && kb) aliveW[e0 >> 6] &= ~kb;
        }
        __syncthreads();
    }
    for (int k = cnt + tid; k < maxOut; k += 1024) out[k] = 0;
    if (tid == 0) out[maxOut] = cnt;
}

// ---------------- launch ----------------
extern "C" void kernel_launch(void* const* d_in, const int* in_sizes, int n_in,
                              void* d_out, int out_size, void* d_ws, size_t ws_size,
                              hipStream_t stream) {
    const float* boxes       = (const float*)d_in[0];
    const float* scores      = (const float*)d_in[1];
    const float* iouThrPtr   = (const float*)d_in[3];
    const float* scoreThrPtr = (const float*)d_in[4];

    int N = in_sizes[0] / 4;
    int maxOut = out_size - 1;
    int nch = 2;
    while (nch * CH < N) nch <<= 1;            // power-of-two chunk count, >=2

    char* ws = (char*)d_ws;
    size_t off = 0;
    auto take = [&](size_t b) { void* p = ws + off; off = (off + b + 255) & ~(size_t)255; return p; };
    u64*   bufA   = (u64*)  take((size_t)nch * TOPK * 8);
    u64*   bufB   = (u64*)  take((size_t)(nch / 2) * TOPK * 8);
    float* sx1    = (float*)take(TOPK * 4);
    float* sy1    = (float*)take(TOPK * 4);
    float* sx2    = (float*)take(TOPK * 4);
    float* sy2    = (float*)take(TOPK * 4);
    float* areas  = (float*)take(TOPK * 4);
    int*   sorig  = (int*)  take(TOPK * 4);
    u64*   validw = (u64*)  take(MW2 * 8);
    int*   validCnt = (int*)take((size_t)nch * 4);
    int*   validTotal = (int*)take(256);
    u64*   maskT  = (u64*)  take((size_t)TOPK * MW2 * 8);
    u64*   diagT  = (u64*)  take((size_t)MW2 * 64 * 8);
    int*   flag   = (int*)  take(256);
    (void)ws_size;

    local_sort_kernel<<<nch, 1024, 0, stream>>>(scores, scoreThrPtr, bufA, validCnt, N);

    u64* src = bufA;
    u64* dst = bufB;
    int cur = nch;
    while (cur > 2) {
        merge_kernel<<<cur / 2, 1024, 0, stream>>>(src, dst);
        u64* tmp = src; src = dst; dst = tmp;
        cur >>= 1;
    }
    merge_final_kernel<<<1, 1024, 0, stream>>>(src, boxes, sx1, sy1, sx2, sy2, areas,
                                               sorig, validw, validCnt, nch, validTotal);

    mask2_kernel<<<dim3(MW2, MW2), 64, 0, stream>>>(sx1, sy1, sx2, sy2, areas, iouThrPtr,
                                                    maskT, diagT);

    scan2_kernel<<<1, SCAN_T, 0, stream>>>(maskT, diagT, validw, sorig, validTotal,
                                           (int*)d_out, flag, maxOut);

    nms_fallback_kernel<<<1, 1024, 0, stream>>>(boxes, scores, iouThrPtr, scoreThrPtr,
                                                flag, (int*)d_out, N, maxOut);
}